// Round 1
// baseline (5780.219 us; speedup 1.0000x reference)
//
#include <hip/hip_runtime.h>
#include <math.h>

#define SEQ   2048
#define BATCH 2
#define NH    16
#define DKD   64
#define DM    1024
#define MTOT  (BATCH*SEQ)   // 4096

// ---------------- Tiled NT SGEMM: C[M][N] = A[M][K] * B[N][K]^T ----------------
// 64x64 output tile, K-tile 16, 256 threads, 4x4 microtile per thread.
#define TM 64
#define TN 64
#define TK 16

__global__ __launch_bounds__(256)
void sgemm_nt(const float* __restrict__ A, const float* __restrict__ Bm,
              float* __restrict__ C, int Kdim, int Ndim)
{
    __shared__ __align__(16) float As[TK][TM + 4];   // [k][m], pad 68 -> conflict-light
    __shared__ __align__(16) float Bs[TK][TN + 4];
    const int t  = threadIdx.x;
    const int tx = t & 15, ty = t >> 4;
    const int m0 = blockIdx.y * TM, n0 = blockIdx.x * TN;
    const int row = t >> 2, kq = t & 3;

    float acc[4][4] = {};

    for (int k0 = 0; k0 < Kdim; k0 += TK) {
        float4 av = *(const float4*)&A [(size_t)(m0 + row) * Kdim + k0 + 4*kq];
        float4 bv = *(const float4*)&Bm[(size_t)(n0 + row) * Kdim + k0 + 4*kq];
        __syncthreads();   // previous tile's reads done before overwrite
        As[4*kq+0][row] = av.x; As[4*kq+1][row] = av.y;
        As[4*kq+2][row] = av.z; As[4*kq+3][row] = av.w;
        Bs[4*kq+0][row] = bv.x; Bs[4*kq+1][row] = bv.y;
        Bs[4*kq+2][row] = bv.z; Bs[4*kq+3][row] = bv.w;
        __syncthreads();
        #pragma unroll
        for (int kk = 0; kk < TK; ++kk) {
            float4 a4 = *(const float4*)&As[kk][ty*4];
            float4 b4 = *(const float4*)&Bs[kk][tx*4];
            float ar[4] = {a4.x, a4.y, a4.z, a4.w};
            float br[4] = {b4.x, b4.y, b4.z, b4.w};
            #pragma unroll
            for (int i = 0; i < 4; ++i)
                #pragma unroll
                for (int j = 0; j < 4; ++j)
                    acc[i][j] += ar[i] * br[j];
        }
    }
    #pragma unroll
    for (int i = 0; i < 4; ++i) {
        float4 v = make_float4(acc[i][0], acc[i][1], acc[i][2], acc[i][3]);
        *(float4*)&C[(size_t)(m0 + ty*4 + i) * Ndim + n0 + tx*4] = v;
    }
}

// ---------------- QKV projection: same GEMM, scatter to [b][h][s][dk] ----------------
__global__ __launch_bounds__(256)
void qkv_gemm(const float* __restrict__ X, const float* __restrict__ Wq,
              const float* __restrict__ Wk, const float* __restrict__ Wv,
              float* __restrict__ Qw, float* __restrict__ Kw, float* __restrict__ Vw)
{
    const float* Bm = (blockIdx.z == 0) ? Wq : (blockIdx.z == 1) ? Wk : Wv;
    float*      dst = (blockIdx.z == 0) ? Qw : (blockIdx.z == 1) ? Kw : Vw;

    __shared__ __align__(16) float As[TK][TM + 4];
    __shared__ __align__(16) float Bs[TK][TN + 4];
    const int t  = threadIdx.x;
    const int tx = t & 15, ty = t >> 4;
    const int m0 = blockIdx.y * TM, n0 = blockIdx.x * TN;
    const int row = t >> 2, kq = t & 3;

    float acc[4][4] = {};

    for (int k0 = 0; k0 < DM; k0 += TK) {
        float4 av = *(const float4*)&X [(size_t)(m0 + row) * DM + k0 + 4*kq];
        float4 bv = *(const float4*)&Bm[(size_t)(n0 + row) * DM + k0 + 4*kq];
        __syncthreads();
        As[4*kq+0][row] = av.x; As[4*kq+1][row] = av.y;
        As[4*kq+2][row] = av.z; As[4*kq+3][row] = av.w;
        Bs[4*kq+0][row] = bv.x; Bs[4*kq+1][row] = bv.y;
        Bs[4*kq+2][row] = bv.z; Bs[4*kq+3][row] = bv.w;
        __syncthreads();
        #pragma unroll
        for (int kk = 0; kk < TK; ++kk) {
            float4 a4 = *(const float4*)&As[kk][ty*4];
            float4 b4 = *(const float4*)&Bs[kk][tx*4];
            float ar[4] = {a4.x, a4.y, a4.z, a4.w};
            float br[4] = {b4.x, b4.y, b4.z, b4.w};
            #pragma unroll
            for (int i = 0; i < 4; ++i)
                #pragma unroll
                for (int j = 0; j < 4; ++j)
                    acc[i][j] += ar[i] * br[j];
        }
    }
    // n0 is a multiple of 64 -> head h constant per block; d = tx*4+j
    const int h = n0 >> 6;
    #pragma unroll
    for (int i = 0; i < 4; ++i) {
        int r  = m0 + ty*4 + i;
        int bb = r >> 11;            // r / SEQ
        int ss = r & (SEQ - 1);
        float4 v = make_float4(acc[i][0], acc[i][1], acc[i][2], acc[i][3]);
        *(float4*)&dst[(((size_t)(bb*NH + h) * SEQ + ss) * DKD) + tx*4] = v;
    }
}

// ---------------- RoPE (interleaved pairs), in place on Q and K ----------------
__global__ __launch_bounds__(256)
void rope_kernel(float* __restrict__ Qw, float* __restrict__ Kw,
                 const int* __restrict__ pos)
{
    int idx = blockIdx.x * 256 + threadIdx.x;        // pair index, 2M total
    int i  = idx & 31;                               // pair within head dim
    int s  = (idx >> 5) & (SEQ - 1);
    // layout [bh][s][dk]: float2 at flat index idx
    float p   = (float)pos[s];
    float inv = powf(10000.0f, -(float)i / 32.0f);   // theta^(-2i/d), d=64
    float ang = p * inv;
    float sn = sinf(ang), cs = cosf(ang);            // precise range reduction

    float2* q2 = (float2*)Qw + idx;
    float2* k2 = (float2*)Kw + idx;
    float2 q = *q2, k = *k2;
    *q2 = make_float2(q.x * cs - q.y * sn, q.x * sn + q.y * cs);
    *k2 = make_float2(k.x * cs - k.y * sn, k.x * sn + k.y * cs);
}

// ---------------- Causal attention: one block per (b,h,q-row) ----------------
__global__ __launch_bounds__(256)
void attn_kernel(const float* __restrict__ Qw, const float* __restrict__ Kw,
                 const float* __restrict__ Vw, float* __restrict__ AO)
{
    const int q  = blockIdx.x;
    const int bh = blockIdx.y;
    const int b  = bh >> 4, h = bh & 15;
    const float* Qr = Qw + ((size_t)bh * SEQ + q) * DKD;
    const float* Kb = Kw + (size_t)bh * SEQ * DKD;
    const float* Vb = Vw + (size_t)bh * SEQ * DKD;

    __shared__ __align__(16) float qrow[DKD];
    __shared__ float sc[SEQ];
    __shared__ float red[8];
    __shared__ float part[4][DKD];

    const int t = threadIdx.x;
    const int kn = q + 1;                       // causal: k <= q
    const float scale = 0.125f;                 // 1/sqrt(64)

    if (t < DKD/4) ((float4*)qrow)[t] = ((const float4*)Qr)[t];
    __syncthreads();

    // scores
    for (int k = t; k < kn; k += 256) {
        const float4* Kr = (const float4*)(Kb + (size_t)k * DKD);
        float a = 0.f;
        #pragma unroll
        for (int i = 0; i < DKD/4; ++i) {
            float4 kv = Kr[i];
            float4 qv = ((const float4*)qrow)[i];   // wave-uniform -> broadcast
            a += kv.x*qv.x + kv.y*qv.y + kv.z*qv.z + kv.w*qv.w;
        }
        sc[k] = a * scale;
    }
    __syncthreads();

    // row max
    float m = -1e30f;
    for (int k = t; k < kn; k += 256) m = fmaxf(m, sc[k]);
    #pragma unroll
    for (int off = 32; off >= 1; off >>= 1) m = fmaxf(m, __shfl_xor(m, off));
    const int wid = t >> 6;
    if ((t & 63) == 0) red[wid] = m;
    __syncthreads();
    m = fmaxf(fmaxf(red[0], red[1]), fmaxf(red[2], red[3]));

    // exp + sum
    float l = 0.f;
    for (int k = t; k < kn; k += 256) { float p = __expf(sc[k] - m); sc[k] = p; l += p; }
    #pragma unroll
    for (int off = 32; off >= 1; off >>= 1) l += __shfl_xor(l, off);
    if ((t & 63) == 0) red[4 + wid] = l;
    __syncthreads();
    l = red[4] + red[5] + red[6] + red[7];

    // PV: wave c handles k = c, c+4, ... (k uniform per wave -> coalesced V)
    const int c = t >> 6, d = t & 63;
    float a = 0.f;
    for (int k = c; k < kn; k += 4) a += sc[k] * Vb[(size_t)k * DKD + d];
    part[c][d] = a;
    __syncthreads();
    if (t < DKD) {
        float o = (part[0][t] + part[1][t] + part[2][t] + part[3][t]) / l;
        AO[((size_t)b * SEQ + q) * DM + h * DKD + t] = o;   // [b][s][h*dk]
    }
}

// ---------------- launch ----------------
extern "C" void kernel_launch(void* const* d_in, const int* in_sizes, int n_in,
                              void* d_out, int out_size, void* d_ws, size_t ws_size,
                              hipStream_t stream)
{
    const float* x   = (const float*)d_in[0];
    const int*   pos = (const int*)  d_in[1];
    const float* Wq  = (const float*)d_in[2];
    const float* Wk  = (const float*)d_in[3];
    const float* Wv  = (const float*)d_in[4];
    const float* Wo  = (const float*)d_in[5];
    float* out = (float*)d_out;

    const size_t TEN = (size_t)BATCH * NH * SEQ * DKD;   // 4M floats
    float* ws = (float*)d_ws;
    float* Qw = ws;
    float* Kw = ws + TEN;
    float* Vw = ws + 2*TEN;
    float* AO = ws + 3*TEN;                              // [b][s][h*dk]

    // QKV projections (+ scatter to [b][h][s][dk])
    qkv_gemm<<<dim3(DM/TN, MTOT/TM, 3), 256, 0, stream>>>(x, Wq, Wk, Wv, Qw, Kw, Vw);

    // RoPE in place on Q and K
    const int pairs = (int)(TEN / 2);                    // 2M
    rope_kernel<<<pairs / 256, 256, 0, stream>>>(Qw, Kw, pos);

    // causal attention
    attn_kernel<<<dim3(SEQ, BATCH*NH), 256, 0, stream>>>(Qw, Kw, Vw, AO);

    // output projection
    sgemm_nt<<<dim3(DM/TN, MTOT/TM), 256, 0, stream>>>(AO, Wo, out, DM, DM);
}

// Round 4
// 977.812 us; speedup vs baseline: 5.9114x; 5.9114x over previous
//
#include <hip/hip_runtime.h>
#include <math.h>

#define SEQ   2048
#define BATCH 2
#define NH    16
#define DKD   64
#define DM    1024
#define MTOT  (BATCH*SEQ)   // 4096

// ---------------- Tiled NT SGEMM: C[M][N] = A[M][K] * B[N][K]^T ----------------
#define TM 64
#define TN 64
#define TK 16

__global__ __launch_bounds__(256)
void sgemm_nt(const float* __restrict__ A, const float* __restrict__ Bm,
              float* __restrict__ C, int Kdim, int Ndim)
{
    __shared__ __align__(16) float As[TK][TM + 4];
    __shared__ __align__(16) float Bs[TK][TN + 4];
    const int t  = threadIdx.x;
    const int tx = t & 15, ty = t >> 4;
    const int m0 = blockIdx.y * TM, n0 = blockIdx.x * TN;
    const int row = t >> 2, kq = t & 3;

    float acc[4][4] = {};

    for (int k0 = 0; k0 < Kdim; k0 += TK) {
        float4 av = *(const float4*)&A [(size_t)(m0 + row) * Kdim + k0 + 4*kq];
        float4 bv = *(const float4*)&Bm[(size_t)(n0 + row) * Kdim + k0 + 4*kq];
        __syncthreads();
        As[4*kq+0][row] = av.x; As[4*kq+1][row] = av.y;
        As[4*kq+2][row] = av.z; As[4*kq+3][row] = av.w;
        Bs[4*kq+0][row] = bv.x; Bs[4*kq+1][row] = bv.y;
        Bs[4*kq+2][row] = bv.z; Bs[4*kq+3][row] = bv.w;
        __syncthreads();
        #pragma unroll
        for (int kk = 0; kk < TK; ++kk) {
            float4 a4 = *(const float4*)&As[kk][ty*4];
            float4 b4 = *(const float4*)&Bs[kk][tx*4];
            float ar[4] = {a4.x, a4.y, a4.z, a4.w};
            float br[4] = {b4.x, b4.y, b4.z, b4.w};
            #pragma unroll
            for (int i = 0; i < 4; ++i)
                #pragma unroll
                for (int j = 0; j < 4; ++j)
                    acc[i][j] += ar[i] * br[j];
        }
    }
    #pragma unroll
    for (int i = 0; i < 4; ++i) {
        float4 v = make_float4(acc[i][0], acc[i][1], acc[i][2], acc[i][3]);
        *(float4*)&C[(size_t)(m0 + ty*4 + i) * Ndim + n0 + tx*4] = v;
    }
}

// ---------------- QKV projection: same GEMM, scatter to [b][h][s][dk] ----------------
__global__ __launch_bounds__(256)
void qkv_gemm(const float* __restrict__ X, const float* __restrict__ Wq,
              const float* __restrict__ Wk, const float* __restrict__ Wv,
              float* __restrict__ Qw, float* __restrict__ Kw, float* __restrict__ Vw)
{
    const float* Bm = (blockIdx.z == 0) ? Wq : (blockIdx.z == 1) ? Wk : Wv;
    float*      dst = (blockIdx.z == 0) ? Qw : (blockIdx.z == 1) ? Kw : Vw;

    __shared__ __align__(16) float As[TK][TM + 4];
    __shared__ __align__(16) float Bs[TK][TN + 4];
    const int t  = threadIdx.x;
    const int tx = t & 15, ty = t >> 4;
    const int m0 = blockIdx.y * TM, n0 = blockIdx.x * TN;
    const int row = t >> 2, kq = t & 3;

    float acc[4][4] = {};

    for (int k0 = 0; k0 < DM; k0 += TK) {
        float4 av = *(const float4*)&X [(size_t)(m0 + row) * DM + k0 + 4*kq];
        float4 bv = *(const float4*)&Bm[(size_t)(n0 + row) * DM + k0 + 4*kq];
        __syncthreads();
        As[4*kq+0][row] = av.x; As[4*kq+1][row] = av.y;
        As[4*kq+2][row] = av.z; As[4*kq+3][row] = av.w;
        Bs[4*kq+0][row] = bv.x; Bs[4*kq+1][row] = bv.y;
        Bs[4*kq+2][row] = bv.z; Bs[4*kq+3][row] = bv.w;
        __syncthreads();
        #pragma unroll
        for (int kk = 0; kk < TK; ++kk) {
            float4 a4 = *(const float4*)&As[kk][ty*4];
            float4 b4 = *(const float4*)&Bs[kk][tx*4];
            float ar[4] = {a4.x, a4.y, a4.z, a4.w};
            float br[4] = {b4.x, b4.y, b4.z, b4.w};
            #pragma unroll
            for (int i = 0; i < 4; ++i)
                #pragma unroll
                for (int j = 0; j < 4; ++j)
                    acc[i][j] += ar[i] * br[j];
        }
    }
    const int h = n0 >> 6;
    #pragma unroll
    for (int i = 0; i < 4; ++i) {
        int r  = m0 + ty*4 + i;
        int bb = r >> 11;
        int ss = r & (SEQ - 1);
        float4 v = make_float4(acc[i][0], acc[i][1], acc[i][2], acc[i][3]);
        *(float4*)&dst[(((size_t)(bb*NH + h) * SEQ + ss) * DKD) + tx*4] = v;
    }
}

// ---------------- RoPE (interleaved pairs), in place on Q and K ----------------
__global__ __launch_bounds__(256)
void rope_kernel(float* __restrict__ Qw, float* __restrict__ Kw,
                 const int* __restrict__ pos)
{
    int idx = blockIdx.x * 256 + threadIdx.x;
    int i  = idx & 31;
    int s  = (idx >> 5) & (SEQ - 1);
    float p   = (float)pos[s];
    float inv = powf(10000.0f, -(float)i / 32.0f);
    float ang = p * inv;
    float sn = sinf(ang), cs = cosf(ang);

    float2* q2 = (float2*)Qw + idx;
    float2* k2 = (float2*)Kw + idx;
    float2 q = *q2, k = *k2;
    *q2 = make_float2(q.x * cs - q.y * sn, q.x * sn + q.y * cs);
    *k2 = make_float2(k.x * cs - k.y * sn, k.x * sn + k.y * cs);
}

// ---------------- Flash attention: 64 q-rows per block, K/V tiles in LDS ----------------
#define BQ 64
#define BK 64

__global__ __launch_bounds__(256)
void flash_attn(const float* __restrict__ Qw, const float* __restrict__ Kw,
                const float* __restrict__ Vw, float* __restrict__ AO)
{
    const int qb = blockIdx.x;
    const int bh = blockIdx.y;
    const int b  = bh >> 4, h = bh & 15;
    const int q0 = qb * BQ;

    __shared__ __align__(16) float Qs[DKD][BQ + 4];   // [d][r] (transposed)
    __shared__ __align__(16) float Ks[DKD][BK + 4];   // [d][c] (transposed)
    __shared__ __align__(16) float Vs[BK][DKD + 4];   // [c][d]
    __shared__ __align__(16) float Ps[BQ][BK + 4];    // [r][c]

    const int t  = threadIdx.x;
    const int tx = t & 15, ty = t >> 4;
    const int lr = t >> 2;             // staging row 0..63
    const int lc = (t & 3) * 16;       // staging d-chunk base

    const float* Qbase = Qw + (size_t)bh * SEQ * DKD;
    const float* Kbase = Kw + (size_t)bh * SEQ * DKD;
    const float* Vbase = Vw + (size_t)bh * SEQ * DKD;

    // stage Q tile (transposed)
    {
        const float* src = Qbase + (size_t)(q0 + lr) * DKD + lc;
        #pragma unroll
        for (int c = 0; c < 4; ++c) {
            float4 v = *(const float4*)(src + 4*c);
            Qs[lc+4*c+0][lr] = v.x; Qs[lc+4*c+1][lr] = v.y;
            Qs[lc+4*c+2][lr] = v.z; Qs[lc+4*c+3][lr] = v.w;
        }
    }

    float m[4], l[4], acc[4][4];
    #pragma unroll
    for (int i = 0; i < 4; ++i) {
        m[i] = -1e30f; l[i] = 0.f;
        #pragma unroll
        for (int j = 0; j < 4; ++j) acc[i][j] = 0.f;
    }

    const int nt = qb + 1;
    for (int kt = 0; kt < nt; ++kt) {
        const int k0 = kt * BK;
        // ---- stage K (transposed) + V (row-major) ----
        {
            const float* ks = Kbase + (size_t)(k0 + lr) * DKD + lc;
            const float* vs = Vbase + (size_t)(k0 + lr) * DKD + lc;
            float4 kv[4], vv[4];
            #pragma unroll
            for (int c = 0; c < 4; ++c) {
                kv[c] = *(const float4*)(ks + 4*c);
                vv[c] = *(const float4*)(vs + 4*c);
            }
            __syncthreads();   // previous tile's Ks/Vs/Ps reads complete
            #pragma unroll
            for (int c = 0; c < 4; ++c) {
                Ks[lc+4*c+0][lr] = kv[c].x; Ks[lc+4*c+1][lr] = kv[c].y;
                Ks[lc+4*c+2][lr] = kv[c].z; Ks[lc+4*c+3][lr] = kv[c].w;
                *(float4*)&Vs[lr][lc + 4*c] = vv[c];
            }
            __syncthreads();
        }

        // ---- S = scale * Q K^T ----
        float s[4][4] = {};
        #pragma unroll 8
        for (int d = 0; d < DKD; ++d) {
            float4 a4 = *(const float4*)&Qs[d][ty*4];
            float4 b4 = *(const float4*)&Ks[d][tx*4];
            float ar[4] = {a4.x, a4.y, a4.z, a4.w};
            float br[4] = {b4.x, b4.y, b4.z, b4.w};
            #pragma unroll
            for (int i = 0; i < 4; ++i)
                #pragma unroll
                for (int j = 0; j < 4; ++j)
                    s[i][j] += ar[i] * br[j];
        }
        const float scale = 0.125f;   // 1/sqrt(64)
        #pragma unroll
        for (int i = 0; i < 4; ++i)
            #pragma unroll
            for (int j = 0; j < 4; ++j)
                s[i][j] *= scale;

        // ---- causal mask (diagonal tile only) ----
        if (k0 == q0) {
            #pragma unroll
            for (int i = 0; i < 4; ++i)
                #pragma unroll
                for (int j = 0; j < 4; ++j)
                    if (tx*4 + j > ty*4 + i) s[i][j] = -1e30f;
        }

        // ---- online softmax update ----
        float p[4][4];
        #pragma unroll
        for (int i = 0; i < 4; ++i) {
            float tm = fmaxf(fmaxf(s[i][0], s[i][1]), fmaxf(s[i][2], s[i][3]));
            #pragma unroll
            for (int off = 8; off >= 1; off >>= 1) tm = fmaxf(tm, __shfl_xor(tm, off));
            float mn = fmaxf(m[i], tm);
            float f  = __expf(m[i] - mn);
            m[i] = mn;
            float ls = 0.f;
            #pragma unroll
            for (int j = 0; j < 4; ++j) { p[i][j] = __expf(s[i][j] - mn); ls += p[i][j]; }
            #pragma unroll
            for (int off = 8; off >= 1; off >>= 1) ls += __shfl_xor(ls, off);
            l[i] = l[i] * f + ls;
            #pragma unroll
            for (int j = 0; j < 4; ++j) acc[i][j] *= f;
        }

        // ---- write P tile, then O += P V ----
        #pragma unroll
        for (int i = 0; i < 4; ++i)
            *(float4*)&Ps[ty*4 + i][tx*4] = make_float4(p[i][0], p[i][1], p[i][2], p[i][3]);
        __syncthreads();

        #pragma unroll 4
        for (int c4 = 0; c4 < BK; c4 += 4) {
            float4 pa[4];
            #pragma unroll
            for (int i = 0; i < 4; ++i) pa[i] = *(const float4*)&Ps[ty*4 + i][c4];
            #pragma unroll
            for (int cc = 0; cc < 4; ++cc) {
                float4 b4 = *(const float4*)&Vs[c4 + cc][tx*4];
                float ar[4];
                ar[0] = (cc==0)?pa[0].x:(cc==1)?pa[0].y:(cc==2)?pa[0].z:pa[0].w;
                ar[1] = (cc==0)?pa[1].x:(cc==1)?pa[1].y:(cc==2)?pa[1].z:pa[1].w;
                ar[2] = (cc==0)?pa[2].x:(cc==1)?pa[2].y:(cc==2)?pa[2].z:pa[2].w;
                ar[3] = (cc==0)?pa[3].x:(cc==1)?pa[3].y:(cc==2)?pa[3].z:pa[3].w;
                float br[4] = {b4.x, b4.y, b4.z, b4.w};
                #pragma unroll
                for (int i = 0; i < 4; ++i)
                    #pragma unroll
                    for (int j = 0; j < 4; ++j)
                        acc[i][j] += ar[i] * br[j];
            }
        }
        // next iteration's pre-store __syncthreads protects Ps/Vs reuse
    }

    // ---- epilogue: normalize and write [b][s][h*dk] ----
    #pragma unroll
    for (int i = 0; i < 4; ++i) {
        float inv = 1.0f / l[i];
        float4 v = make_float4(acc[i][0]*inv, acc[i][1]*inv, acc[i][2]*inv, acc[i][3]*inv);
        *(float4*)&AO[((size_t)b * SEQ + q0 + ty*4 + i) * DM + h * DKD + tx*4] = v;
    }
}

// ---------------- launch ----------------
extern "C" void kernel_launch(void* const* d_in, const int* in_sizes, int n_in,
                              void* d_out, int out_size, void* d_ws, size_t ws_size,
                              hipStream_t stream)
{
    const float* x   = (const float*)d_in[0];
    const int*   pos = (const int*)  d_in[1];
    const float* Wq  = (const float*)d_in[2];
    const float* Wk  = (const float*)d_in[3];
    const float* Wv  = (const float*)d_in[4];
    const float* Wo  = (const float*)d_in[5];
    float* out = (float*)d_out;

    const size_t TEN = (size_t)BATCH * NH * SEQ * DKD;   // 4M floats
    float* ws = (float*)d_ws;
    float* Qw = ws;
    float* Kw = ws + TEN;
    float* Vw = ws + 2*TEN;
    float* AO = ws + 3*TEN;                              // [b][s][h*dk]

    qkv_gemm<<<dim3(DM/TN, MTOT/TM, 3), 256, 0, stream>>>(x, Wq, Wk, Wv, Qw, Kw, Vw);

    const int pairs = (int)(TEN / 2);
    rope_kernel<<<pairs / 256, 256, 0, stream>>>(Qw, Kw, pos);

    flash_attn<<<dim3(SEQ/BQ, BATCH*NH), 256, 0, stream>>>(Qw, Kw, Vw, AO);

    sgemm_nt<<<dim3(DM/TN, MTOT/TM), 256, 0, stream>>>(AO, Wo, out, DM, DM);
}

// Round 7
// 210.678 us; speedup vs baseline: 27.4363x; 4.6413x over previous
//
#include <hip/hip_runtime.h>
#include <math.h>

#define SEQ   2048
#define BATCH 2
#define NH    16
#define DKD   64
#define DM    1024
#define MTOT  (BATCH*SEQ)   // 4096

typedef short bf16x8 __attribute__((ext_vector_type(8)));      // 8 bf16 (4 VGPR)
typedef float f32x4  __attribute__((ext_vector_type(4)));      // MFMA C/D
typedef unsigned short u16x4 __attribute__((ext_vector_type(4)));

#define MFMA_B16(a,b,c) __builtin_amdgcn_mfma_f32_16x16x32_bf16((a),(b),(c),0,0,0)

__device__ __forceinline__ unsigned short f2bf(float f) {
    union { float f; unsigned int u; } v; v.f = f;
    unsigned int r = v.u + 0x7FFFu + ((v.u >> 16) & 1u);   // RNE
    return (unsigned short)(r >> 16);
}
__device__ __forceinline__ float bf2f(unsigned short h) {
    union { unsigned int u; float f; } v; v.u = ((unsigned int)h) << 16;
    return v.f;
}
__device__ __forceinline__ void gload16(const void* g, void* l) {
    __builtin_amdgcn_global_load_lds(
        (const __attribute__((address_space(1))) unsigned int*)g,
        (__attribute__((address_space(3))) unsigned int*)l, 16, 0, 0);
}

// ---------------- fp32 -> bf16 conversion (vectorized) ----------------
__global__ __launch_bounds__(256)
void f32_to_bf16_vec(const float* __restrict__ src, unsigned short* __restrict__ dst, int n4)
{
    int i = blockIdx.x * 256 + threadIdx.x;
    if (i >= n4) return;
    float4 v = ((const float4*)src)[i];
    u16x4 o = { f2bf(v.x), f2bf(v.y), f2bf(v.z), f2bf(v.w) };
    *(u16x4*)&dst[(size_t)i * 4] = o;
}

// ---------------- RoPE in place on bf16 Q/K  [bh][s][64] ----------------
__global__ __launch_bounds__(256)
void rope_bf16(unsigned short* __restrict__ Qb, unsigned short* __restrict__ Kb,
               const int* __restrict__ pos)
{
    int g = blockIdx.x * 256 + threadIdx.x;      // 2M ushort4-groups (Q then K)
    int tsel = g >> 20;
    int i = g & ((1 << 20) - 1);
    unsigned short* base = tsel ? Kb : Qb;
    int d4 = i & 15;                             // float4-group within row of 64
    int s  = (i >> 4) & (SEQ - 1);
    float P = (float)pos[s];
    const float NEG_L2 = -0.41524101186092103f;  // -log2(10000)/32
    int p0 = d4 * 2, p1 = p0 + 1;
    float a0 = P * exp2f((float)p0 * NEG_L2);
    float a1 = P * exp2f((float)p1 * NEG_L2);
    float s0, c0, s1, c1;
    sincosf(a0, &s0, &c0);
    sincosf(a1, &s1, &c1);

    u16x4 v = *(u16x4*)&base[(size_t)i * 4];
    float x0 = bf2f(v[0]), x1 = bf2f(v[1]), x2 = bf2f(v[2]), x3 = bf2f(v[3]);
    u16x4 o = { f2bf(x0 * c0 - x1 * s0), f2bf(x0 * s0 + x1 * c0),
                f2bf(x2 * c1 - x3 * s1), f2bf(x2 * s1 + x3 * c1) };
    *(u16x4*)&base[(size_t)i * 4] = o;
}

// ---------------- MFMA GEMM: C[M][N] = A[M][K] x B[N][K]^T, bf16 in / f32 acc ----
// 128x128 tile, BK=32, 4 waves (2x2) of 64x64, global_load_lds staging (m97 style)
// MODE 0: N=3072, epilogue scatters Q,K (bf16 [bh][s][d]) and V transposed ([bh][d][s])
// MODE 1: N=1024, epilogue writes fp32 row-major C
template<int MODE>
__global__ __launch_bounds__(256)
void gemm_mfma(const unsigned short* __restrict__ A, const unsigned short* __restrict__ B,
               unsigned short* __restrict__ Qb, unsigned short* __restrict__ Kb,
               unsigned short* __restrict__ VTb, float* __restrict__ Cf)
{
    const int t = threadIdx.x;
    const int w = t >> 6, l = t & 63, lid = l & 15, hi = (l >> 4) * 16;
    const int wm = w >> 1, wn = w & 1;
    const int m0 = blockIdx.y * 128, n0 = blockIdx.x * 128;

    __shared__ __align__(16) char At[2][8192];   // [128 m][32 k] bf16, 64 B rows
    __shared__ __align__(16) char Bt[2][8192];   // [128 n][32 k] bf16

    f32x4 acc[4][4];
    const f32x4 z4 = {0.f, 0.f, 0.f, 0.f};
    #pragma unroll
    for (int i = 0; i < 4; ++i)
        #pragma unroll
        for (int j = 0; j < 4; ++j) acc[i][j] = z4;

    const char* Ab = (const char*)A;
    const char* Bb = (const char*)B;

    auto stage = [&](int buf, int kt) {
        const int kbyte = kt * 64;               // k0*2
        #pragma unroll
        for (int i = 0; i < 2; ++i) {
            int o   = i * 4096 + t * 16;
            int row = o >> 6, cb = o & 63;
            char* lbase_a = At[buf] + i * 4096 + (t >> 6) * 1024;
            char* lbase_b = Bt[buf] + i * 4096 + (t >> 6) * 1024;
            gload16(Ab + (size_t)(m0 + row) * 2048 + kbyte + cb, lbase_a);
            gload16(Bb + (size_t)(n0 + row) * 2048 + kbyte + cb, lbase_b);
        }
    };

    stage(0, 0);
    __syncthreads();

    const int NKT = DM / 32;                     // 32
    for (int kt = 0; kt < NKT; ++kt) {
        const int cur = kt & 1;
        if (kt + 1 < NKT) stage(cur ^ 1, kt + 1);

        bf16x8 af[4], bfr[4];
        #pragma unroll
        for (int mf = 0; mf < 4; ++mf)
            af[mf] = *(const bf16x8*)(At[cur] + (wm * 64 + mf * 16 + lid) * 64 + hi);
        #pragma unroll
        for (int nf = 0; nf < 4; ++nf)
            bfr[nf] = *(const bf16x8*)(Bt[cur] + (wn * 64 + nf * 16 + lid) * 64 + hi);
        #pragma unroll
        for (int mf = 0; mf < 4; ++mf)
            #pragma unroll
            for (int nf = 0; nf < 4; ++nf)
                acc[mf][nf] = MFMA_B16(af[mf], bfr[nf], acc[mf][nf]);

        __syncthreads();
    }

    // ---- epilogue ----
    if (MODE == 1) {
        #pragma unroll
        for (int mf = 0; mf < 4; ++mf)
            #pragma unroll
            for (int nf = 0; nf < 4; ++nf) {
                int ncol = n0 + wn * 64 + nf * 16 + lid;
                #pragma unroll
                for (int jj = 0; jj < 4; ++jj) {
                    int mrow = m0 + wm * 64 + mf * 16 + (l >> 4) * 4 + jj;
                    Cf[(size_t)mrow * DM + ncol] = acc[mf][nf][jj];
                }
            }
    } else {
        const int z = n0 >> 10;                  // 0:Q 1:K 2:V
        const int nbase = n0 & 1023;
        #pragma unroll
        for (int mf = 0; mf < 4; ++mf)
            #pragma unroll
            for (int nf = 0; nf < 4; ++nf) {
                int ncol = nbase + wn * 64 + nf * 16 + lid;
                int h = ncol >> 6, d = ncol & 63;
                int mbase = m0 + wm * 64 + mf * 16 + (l >> 4) * 4;
                int b = mbase >> 11, s0v = mbase & 2047;
                if (z == 2) {
                    u16x4 pk = { f2bf(acc[mf][nf][0]), f2bf(acc[mf][nf][1]),
                                 f2bf(acc[mf][nf][2]), f2bf(acc[mf][nf][3]) };
                    *(u16x4*)&VTb[((size_t)(b * NH + h) * DKD + d) * SEQ + s0v] = pk;
                } else {
                    unsigned short* dst = (z == 0) ? Qb : Kb;
                    #pragma unroll
                    for (int jj = 0; jj < 4; ++jj)
                        dst[((size_t)(b * NH + h) * SEQ + (s0v + jj)) * DKD + d] =
                            f2bf(acc[mf][nf][jj]);
                }
            }
    }
}

// ---------------- MFMA flash attention ----------------
// grid (32 q-tiles, 32 bh); 256 thr = 4 waves, wave w owns q-rows [16w,16w+16)
// K tile [64 key][64 d] bf16, VT tile [64 d][64 key] bf16, both XOR-swizzled
// (LDS linear dest + inverse-swizzled global source; reads apply same XOR)
__global__ __launch_bounds__(256)
void flash_mfma(const unsigned short* __restrict__ Qb, const unsigned short* __restrict__ Kb,
                const unsigned short* __restrict__ VTb, unsigned short* __restrict__ AOb)
{
    const int qb = blockIdx.x, bh = blockIdx.y;
    const int b = bh >> 4, h = bh & 15;
    const int q0 = qb * 64;
    const int t = threadIdx.x, w = t >> 6, l = t & 63, lid = l & 15, hi = (l >> 4) * 16;

    __shared__ __align__(16) char Kt[2][8192];
    __shared__ __align__(16) char Vt[2][8192];
    __shared__ __align__(16) char Pt[8192];

    const char* Kbh = (const char*)(Kb  + (size_t)bh * SEQ * DKD);
    const char* Vbh = (const char*)(VTb + (size_t)bh * SEQ * DKD);
    const char* Qbh = (const char*)(Qb  + (size_t)bh * SEQ * DKD);

    // Q A-fragments straight from global (row 128 B, 16 B per lane)
    const int qrow = w * 16 + lid;
    bf16x8 qf[2];
    qf[0] = *(const bf16x8*)(Qbh + (size_t)(q0 + qrow) * 128 + 0  + hi);
    qf[1] = *(const bf16x8*)(Qbh + (size_t)(q0 + qrow) * 128 + 64 + hi);

    f32x4 o[4];
    const f32x4 z4 = {0.f, 0.f, 0.f, 0.f};
    #pragma unroll
    for (int nf = 0; nf < 4; ++nf) o[nf] = z4;
    float m[4]  = {-1e30f, -1e30f, -1e30f, -1e30f};
    float lsum[4] = {0.f, 0.f, 0.f, 0.f};

    auto stage = [&](int buf, int kt) {
        const int k0 = kt * 64;
        #pragma unroll
        for (int i = 0; i < 2; ++i) {
            int o_   = i * 4096 + t * 16;
            int row  = o_ >> 7, cl = o_ & 127;
            int sw   = (row & 7) << 4;
            char* lK = Kt[buf] + i * 4096 + (t >> 6) * 1024;
            char* lV = Vt[buf] + i * 4096 + (t >> 6) * 1024;
            gload16(Kbh + (size_t)(k0 + row) * 128 + (cl ^ sw), lK);        // K rows: keys
            gload16(Vbh + (size_t)row * (SEQ * 2) + k0 * 2 + (cl ^ sw), lV); // VT rows: d
        }
    };

    const int nt = qb + 1;
    stage(0, 0);
    __syncthreads();

    for (int kt = 0; kt < nt; ++kt) {
        const int cur = kt & 1;
        if (kt + 1 < nt) stage(cur ^ 1, kt + 1);

        // ---- S = Q K^T (per wave: 16 q x 64 key) ----
        f32x4 sf[4];
        #pragma unroll
        for (int nf = 0; nf < 4; ++nf) {
            f32x4 a = z4;
            #pragma unroll
            for (int ks = 0; ks < 2; ++ks) {
                int r  = nf * 16 + lid;
                int cb = ks * 64 + hi;
                bf16x8 kfr = *(const bf16x8*)(Kt[cur] + r * 128 + (cb ^ ((r & 7) << 4)));
                a = MFMA_B16(qf[ks], kfr, a);
            }
            sf[nf] = a;
        }
        #pragma unroll
        for (int nf = 0; nf < 4; ++nf)
            #pragma unroll
            for (int jj = 0; jj < 4; ++jj)
                sf[nf][jj] *= 0.125f;

        // ---- causal mask on the diagonal tile ----
        if (kt == qb) {
            #pragma unroll
            for (int nf = 0; nf < 4; ++nf) {
                int col = nf * 16 + lid;
                #pragma unroll
                for (int jj = 0; jj < 4; ++jj) {
                    int qq = w * 16 + (l >> 4) * 4 + jj;
                    if (col > qq) sf[nf][jj] = -1e30f;
                }
            }
        }

        // ---- online softmax (rows are wave-private; 16-lane shfl reduce) ----
        float fsc[4];
        #pragma unroll
        for (int jj = 0; jj < 4; ++jj) {
            float tm = fmaxf(fmaxf(sf[0][jj], sf[1][jj]), fmaxf(sf[2][jj], sf[3][jj]));
            tm = fmaxf(tm, __shfl_xor(tm, 1));
            tm = fmaxf(tm, __shfl_xor(tm, 2));
            tm = fmaxf(tm, __shfl_xor(tm, 4));
            tm = fmaxf(tm, __shfl_xor(tm, 8));
            float mn = fmaxf(m[jj], tm);
            fsc[jj] = __expf(m[jj] - mn);
            m[jj] = mn;
        }
        float ls[4] = {0.f, 0.f, 0.f, 0.f};
        unsigned short pw[4][4];
        #pragma unroll
        for (int nf = 0; nf < 4; ++nf)
            #pragma unroll
            for (int jj = 0; jj < 4; ++jj) {
                float p = __expf(sf[nf][jj] - m[jj]);
                ls[jj] += p;
                pw[nf][jj] = f2bf(p);
            }
        #pragma unroll
        for (int jj = 0; jj < 4; ++jj) {
            float s4 = ls[jj];
            s4 += __shfl_xor(s4, 1);
            s4 += __shfl_xor(s4, 2);
            s4 += __shfl_xor(s4, 4);
            s4 += __shfl_xor(s4, 8);
            lsum[jj] = lsum[jj] * fsc[jj] + s4;
        }
        #pragma unroll
        for (int nf = 0; nf < 4; ++nf)
            #pragma unroll
            for (int jj = 0; jj < 4; ++jj)
                o[nf][jj] *= fsc[jj];

        // ---- write P tile (bf16, swizzled; rows wave-private, no barrier) ----
        #pragma unroll
        for (int nf = 0; nf < 4; ++nf)
            #pragma unroll
            for (int jj = 0; jj < 4; ++jj) {
                int qq = w * 16 + (l >> 4) * 4 + jj;
                int cb = 2 * (nf * 16 + lid);
                *(unsigned short*)(Pt + qq * 128 + (cb ^ ((qq & 7) << 4))) = pw[nf][jj];
            }

        // ---- O += P V ----
        #pragma unroll
        for (int ks = 0; ks < 2; ++ks) {
            int cb = ks * 64 + hi;
            int qr = w * 16 + lid;
            bf16x8 pa = *(const bf16x8*)(Pt + qr * 128 + (cb ^ ((qr & 7) << 4)));
            #pragma unroll
            for (int nf = 0; nf < 4; ++nf) {
                int dr = nf * 16 + lid;
                bf16x8 vb = *(const bf16x8*)(Vt[cur] + dr * 128 + (cb ^ ((dr & 7) << 4)));
                o[nf] = MFMA_B16(pa, vb, o[nf]);
            }
        }

        __syncthreads();   // drains staged loads; protects buffer reuse
    }

    // ---- epilogue: AO bf16 [b*S+s][h*64+d] ----
    float inv[4];
    #pragma unroll
    for (int jj = 0; jj < 4; ++jj) inv[jj] = 1.0f / lsum[jj];
    #pragma unroll
    for (int nf = 0; nf < 4; ++nf)
        #pragma unroll
        for (int jj = 0; jj < 4; ++jj) {
            int srow = q0 + w * 16 + (l >> 4) * 4 + jj;
            int col  = h * 64 + nf * 16 + lid;
            AOb[((size_t)b * SEQ + srow) * DM + col] = f2bf(o[nf][jj] * inv[jj]);
        }
}

// ---------------- launch ----------------
extern "C" void kernel_launch(void* const* d_in, const int* in_sizes, int n_in,
                              void* d_out, int out_size, void* d_ws, size_t ws_size,
                              hipStream_t stream)
{
    const float* x   = (const float*)d_in[0];
    const int*   pos = (const int*)  d_in[1];
    const float* Wq  = (const float*)d_in[2];
    const float* Wk  = (const float*)d_in[3];
    const float* Wv  = (const float*)d_in[4];
    const float* Wo  = (const float*)d_in[5];
    float* out = (float*)d_out;

    const size_t M1 = 1u << 20;                 // 1M elements
    unsigned short* ws  = (unsigned short*)d_ws;
    unsigned short* Xb    = ws;                 // 4M
    unsigned short* Wqkvb = ws + 4 * M1;        // 3M (Wq|Wk|Wv rows)
    unsigned short* Wob   = ws + 7 * M1;        // 1M
    unsigned short* Qbf   = ws + 8 * M1;        // 4M  [bh][s][64]
    unsigned short* Kbf   = ws + 12 * M1;       // 4M  [bh][s][64]
    unsigned short* VTb   = ws + 16 * M1;       // 4M  [bh][64][s]
    unsigned short* AOb   = ws + 20 * M1;       // 4M  [b*s][1024]
    // total 48 MB

    // fp32 -> bf16
    f32_to_bf16_vec<<<4096, 256, 0, stream>>>(x,  Xb,           (int)M1);
    f32_to_bf16_vec<<<1024, 256, 0, stream>>>(Wq, Wqkvb,        (int)(M1 / 4));
    f32_to_bf16_vec<<<1024, 256, 0, stream>>>(Wk, Wqkvb + M1,   (int)(M1 / 4));
    f32_to_bf16_vec<<<1024, 256, 0, stream>>>(Wv, Wqkvb + 2*M1, (int)(M1 / 4));
    f32_to_bf16_vec<<<1024, 256, 0, stream>>>(Wo, Wob,          (int)(M1 / 4));

    // QKV projection (epilogue scatters Q,K row-major; V transposed)
    gemm_mfma<0><<<dim3(24, 32), 256, 0, stream>>>(Xb, Wqkvb, Qbf, Kbf, VTb, nullptr);

    // RoPE in place on bf16 Q/K
    rope_bf16<<<8192, 256, 0, stream>>>(Qbf, Kbf, pos);

    // flash attention
    flash_mfma<<<dim3(SEQ / 64, BATCH * NH), 256, 0, stream>>>(Qbf, Kbf, VTb, AOb);

    // output projection
    gemm_mfma<1><<<dim3(8, 32), 256, 0, stream>>>(AOb, Wob, nullptr, nullptr, nullptr, out);
}

// Round 8
// 157.927 us; speedup vs baseline: 36.6005x; 1.3340x over previous
//
#include <hip/hip_runtime.h>
#include <math.h>

#define SEQ   2048
#define BATCH 2
#define NH    16
#define DKD   64
#define DM    1024
#define MTOT  (BATCH*SEQ)   // 4096

typedef short bf16x8 __attribute__((ext_vector_type(8)));      // 8 bf16 (4 VGPR)
typedef float f32x4  __attribute__((ext_vector_type(4)));      // MFMA C/D
typedef unsigned short u16x4 __attribute__((ext_vector_type(4)));

#define MFMA_B16(a,b,c) __builtin_amdgcn_mfma_f32_16x16x32_bf16((a),(b),(c),0,0,0)

__device__ __forceinline__ unsigned short f2bf(float f) {
    union { float f; unsigned int u; } v; v.f = f;
    unsigned int r = v.u + 0x7FFFu + ((v.u >> 16) & 1u);   // RNE
    return (unsigned short)(r >> 16);
}
__device__ __forceinline__ float bf2f(unsigned short h) {
    union { unsigned int u; float f; } v; v.u = ((unsigned int)h) << 16;
    return v.f;
}
__device__ __forceinline__ void gload16(const void* g, void* l) {
    __builtin_amdgcn_global_load_lds(
        (const __attribute__((address_space(1))) unsigned int*)g,
        (__attribute__((address_space(3))) unsigned int*)l, 16, 0, 0);
}

// ---------------- fp32 -> bf16: x + Wq + Wk + Wv + Wo in ONE launch ----------------
// 2M float4-groups total: [0,1M) = x ; then 4 x 256K for the weights.
__global__ __launch_bounds__(256)
void convert_all(const float* __restrict__ x,  const float* __restrict__ Wq,
                 const float* __restrict__ Wk, const float* __restrict__ Wv,
                 const float* __restrict__ Wo,
                 unsigned short* __restrict__ Xb, unsigned short* __restrict__ Wqkvb,
                 unsigned short* __restrict__ Wob)
{
    int i = blockIdx.x * 256 + threadIdx.x;          // 0 .. 2M-1
    const float* src;
    unsigned short* dst;
    size_t off;
    if (i < (1 << 20)) {
        src = x; dst = Xb; off = (size_t)i;
    } else {
        int j = i - (1 << 20);
        int wsel = j >> 18;                          // 0..3
        off = (size_t)(j & ((1 << 18) - 1));
        src = (wsel == 0) ? Wq : (wsel == 1) ? Wk : (wsel == 2) ? Wv : Wo;
        dst = (wsel < 3) ? Wqkvb + (size_t)wsel * (1u << 20) : Wob;
    }
    float4 v = ((const float4*)src)[off];
    u16x4 o = { f2bf(v.x), f2bf(v.y), f2bf(v.z), f2bf(v.w) };
    *(u16x4*)&dst[off * 4] = o;
}

// ---------------- RoPE in place on bf16 Q/K  [bh][s][64] ----------------
__global__ __launch_bounds__(256)
void rope_bf16(unsigned short* __restrict__ Qb, unsigned short* __restrict__ Kb,
               const int* __restrict__ pos)
{
    int g = blockIdx.x * 256 + threadIdx.x;      // 2M ushort4-groups (Q then K)
    int tsel = g >> 20;
    int i = g & ((1 << 20) - 1);
    unsigned short* base = tsel ? Kb : Qb;
    int d4 = i & 15;                             // float4-group within row of 64
    int s  = (i >> 4) & (SEQ - 1);
    float P = (float)pos[s];
    const float NEG_L2 = -0.41524101186092103f;  // -log2(10000)/32
    int p0 = d4 * 2, p1 = p0 + 1;
    float a0 = P * exp2f((float)p0 * NEG_L2);
    float a1 = P * exp2f((float)p1 * NEG_L2);
    float s0, c0, s1, c1;
    sincosf(a0, &s0, &c0);
    sincosf(a1, &s1, &c1);

    u16x4 v = *(u16x4*)&base[(size_t)i * 4];
    float x0 = bf2f(v[0]), x1 = bf2f(v[1]), x2 = bf2f(v[2]), x3 = bf2f(v[3]);
    u16x4 o = { f2bf(x0 * c0 - x1 * s0), f2bf(x0 * s0 + x1 * c0),
                f2bf(x2 * c1 - x3 * s1), f2bf(x2 * s1 + x3 * c1) };
    *(u16x4*)&base[(size_t)i * 4] = o;
}

// ---------------- MFMA GEMM: C[M][N] = A[M][K] x B[N][K]^T, bf16 in / f32 acc ----
// 128x128 tile, BK=32, 4 waves (2x2) of 64x64, global_load_lds staging (m97 style)
// MODE 0: N=3072, epilogue scatters Q,K (bf16 [bh][s][d]) and V transposed ([bh][d][s])
// MODE 1: N=1024, epilogue writes fp32 row-major C
template<int MODE>
__global__ __launch_bounds__(256)
void gemm_mfma(const unsigned short* __restrict__ A, const unsigned short* __restrict__ B,
               unsigned short* __restrict__ Qb, unsigned short* __restrict__ Kb,
               unsigned short* __restrict__ VTb, float* __restrict__ Cf)
{
    const int t = threadIdx.x;
    const int w = t >> 6, l = t & 63, lid = l & 15, hi = (l >> 4) * 16;
    const int wm = w >> 1, wn = w & 1;
    const int m0 = blockIdx.y * 128, n0 = blockIdx.x * 128;

    __shared__ __align__(16) char At[2][8192];   // [128 m][32 k] bf16, 64 B rows
    __shared__ __align__(16) char Bt[2][8192];   // [128 n][32 k] bf16

    f32x4 acc[4][4];
    const f32x4 z4 = {0.f, 0.f, 0.f, 0.f};
    #pragma unroll
    for (int i = 0; i < 4; ++i)
        #pragma unroll
        for (int j = 0; j < 4; ++j) acc[i][j] = z4;

    const char* Ab = (const char*)A;
    const char* Bb = (const char*)B;

    auto stage = [&](int buf, int kt) {
        const int kbyte = kt * 64;               // k0*2
        #pragma unroll
        for (int i = 0; i < 2; ++i) {
            int o   = i * 4096 + t * 16;
            int row = o >> 6, cb = o & 63;
            char* lbase_a = At[buf] + i * 4096 + (t >> 6) * 1024;
            char* lbase_b = Bt[buf] + i * 4096 + (t >> 6) * 1024;
            gload16(Ab + (size_t)(m0 + row) * 2048 + kbyte + cb, lbase_a);
            gload16(Bb + (size_t)(n0 + row) * 2048 + kbyte + cb, lbase_b);
        }
    };

    stage(0, 0);
    __syncthreads();

    const int NKT = DM / 32;                     // 32
    for (int kt = 0; kt < NKT; ++kt) {
        const int cur = kt & 1;
        if (kt + 1 < NKT) stage(cur ^ 1, kt + 1);

        bf16x8 af[4], bfr[4];
        #pragma unroll
        for (int mf = 0; mf < 4; ++mf)
            af[mf] = *(const bf16x8*)(At[cur] + (wm * 64 + mf * 16 + lid) * 64 + hi);
        #pragma unroll
        for (int nf = 0; nf < 4; ++nf)
            bfr[nf] = *(const bf16x8*)(Bt[cur] + (wn * 64 + nf * 16 + lid) * 64 + hi);
        #pragma unroll
        for (int mf = 0; mf < 4; ++mf)
            #pragma unroll
            for (int nf = 0; nf < 4; ++nf)
                acc[mf][nf] = MFMA_B16(af[mf], bfr[nf], acc[mf][nf]);

        __syncthreads();
    }

    // ---- epilogue ----
    if (MODE == 1) {
        #pragma unroll
        for (int mf = 0; mf < 4; ++mf)
            #pragma unroll
            for (int nf = 0; nf < 4; ++nf) {
                int ncol = n0 + wn * 64 + nf * 16 + lid;
                #pragma unroll
                for (int jj = 0; jj < 4; ++jj) {
                    int mrow = m0 + wm * 64 + mf * 16 + (l >> 4) * 4 + jj;
                    Cf[(size_t)mrow * DM + ncol] = acc[mf][nf][jj];
                }
            }
    } else {
        const int z = n0 >> 10;                  // 0:Q 1:K 2:V
        const int nbase = n0 & 1023;
        #pragma unroll
        for (int mf = 0; mf < 4; ++mf)
            #pragma unroll
            for (int nf = 0; nf < 4; ++nf) {
                int ncol = nbase + wn * 64 + nf * 16 + lid;
                int h = ncol >> 6, d = ncol & 63;
                int mbase = m0 + wm * 64 + mf * 16 + (l >> 4) * 4;
                int b = mbase >> 11, s0v = mbase & 2047;
                if (z == 2) {
                    u16x4 pk = { f2bf(acc[mf][nf][0]), f2bf(acc[mf][nf][1]),
                                 f2bf(acc[mf][nf][2]), f2bf(acc[mf][nf][3]) };
                    *(u16x4*)&VTb[((size_t)(b * NH + h) * DKD + d) * SEQ + s0v] = pk;
                } else {
                    unsigned short* dst = (z == 0) ? Qb : Kb;
                    #pragma unroll
                    for (int jj = 0; jj < 4; ++jj)
                        dst[((size_t)(b * NH + h) * SEQ + (s0v + jj)) * DKD + d] =
                            f2bf(acc[mf][nf][jj]);
                }
            }
    }
}

// ---------------- MFMA flash attention, load-balanced q-tile pairs ----------------
// grid (16, 32); block bx processes q-tiles (31-bx) then (bx): work = 33 tile-iters
// for every block. 512 blocks = 2/CU, all resident, zero imbalance.
// K tile [64 key][64 d] bf16, VT tile [64 d][64 key] bf16, both XOR-swizzled
// (LDS linear dest + inverse-swizzled global source; reads apply same XOR)
__global__ __launch_bounds__(256)
void flash_mfma(const unsigned short* __restrict__ Qb, const unsigned short* __restrict__ Kb,
                const unsigned short* __restrict__ VTb, unsigned short* __restrict__ AOb)
{
    const int bh = blockIdx.y;
    const int b = bh >> 4, h = bh & 15;
    const int t = threadIdx.x, w = t >> 6, l = t & 63, lid = l & 15, hi = (l >> 4) * 16;

    __shared__ __align__(16) char Kt[2][8192];
    __shared__ __align__(16) char Vt[2][8192];
    __shared__ __align__(16) char Pt[8192];

    const char* Kbh = (const char*)(Kb  + (size_t)bh * SEQ * DKD);
    const char* Vbh = (const char*)(VTb + (size_t)bh * SEQ * DKD);
    const char* Qbh = (const char*)(Qb  + (size_t)bh * SEQ * DKD);

    const f32x4 z4 = {0.f, 0.f, 0.f, 0.f};
    const int qrow = w * 16 + lid;

    #pragma unroll 1
    for (int phase = 0; phase < 2; ++phase) {
        const int qb = phase ? (int)blockIdx.x : (31 - (int)blockIdx.x);  // heavy first
        const int q0 = qb * 64;

        // Q A-fragments straight from global (row 128 B, 16 B per lane)
        bf16x8 qf[2];
        qf[0] = *(const bf16x8*)(Qbh + (size_t)(q0 + qrow) * 128 + 0  + hi);
        qf[1] = *(const bf16x8*)(Qbh + (size_t)(q0 + qrow) * 128 + 64 + hi);

        f32x4 o[4];
        #pragma unroll
        for (int nf = 0; nf < 4; ++nf) o[nf] = z4;
        float m[4]  = {-1e30f, -1e30f, -1e30f, -1e30f};
        float lsum[4] = {0.f, 0.f, 0.f, 0.f};

        auto stage = [&](int buf, int kt) {
            const int k0 = kt * 64;
            #pragma unroll
            for (int i = 0; i < 2; ++i) {
                int o_   = i * 4096 + t * 16;
                int row  = o_ >> 7, cl = o_ & 127;
                int sw   = (row & 7) << 4;
                char* lK = Kt[buf] + i * 4096 + (t >> 6) * 1024;
                char* lV = Vt[buf] + i * 4096 + (t >> 6) * 1024;
                gload16(Kbh + (size_t)(k0 + row) * 128 + (cl ^ sw), lK);         // K rows: keys
                gload16(Vbh + (size_t)row * (SEQ * 2) + k0 * 2 + (cl ^ sw), lV); // VT rows: d
            }
        };

        const int nt = qb + 1;
        stage(0, 0);
        __syncthreads();

        for (int kt = 0; kt < nt; ++kt) {
            const int cur = kt & 1;
            if (kt + 1 < nt) stage(cur ^ 1, kt + 1);

            // ---- S = Q K^T (per wave: 16 q x 64 key) ----
            f32x4 sf[4];
            #pragma unroll
            for (int nf = 0; nf < 4; ++nf) {
                f32x4 a = z4;
                #pragma unroll
                for (int ks = 0; ks < 2; ++ks) {
                    int r  = nf * 16 + lid;
                    int cb = ks * 64 + hi;
                    bf16x8 kfr = *(const bf16x8*)(Kt[cur] + r * 128 + (cb ^ ((r & 7) << 4)));
                    a = MFMA_B16(qf[ks], kfr, a);
                }
                sf[nf] = a;
            }
            #pragma unroll
            for (int nf = 0; nf < 4; ++nf)
                #pragma unroll
                for (int jj = 0; jj < 4; ++jj)
                    sf[nf][jj] *= 0.125f;

            // ---- causal mask on the diagonal tile ----
            if (kt == qb) {
                #pragma unroll
                for (int nf = 0; nf < 4; ++nf) {
                    int col = nf * 16 + lid;
                    #pragma unroll
                    for (int jj = 0; jj < 4; ++jj) {
                        int qq = w * 16 + (l >> 4) * 4 + jj;
                        if (col > qq) sf[nf][jj] = -1e30f;
                    }
                }
            }

            // ---- online softmax (rows are wave-private; 16-lane shfl reduce) ----
            float fsc[4];
            #pragma unroll
            for (int jj = 0; jj < 4; ++jj) {
                float tm = fmaxf(fmaxf(sf[0][jj], sf[1][jj]), fmaxf(sf[2][jj], sf[3][jj]));
                tm = fmaxf(tm, __shfl_xor(tm, 1));
                tm = fmaxf(tm, __shfl_xor(tm, 2));
                tm = fmaxf(tm, __shfl_xor(tm, 4));
                tm = fmaxf(tm, __shfl_xor(tm, 8));
                float mn = fmaxf(m[jj], tm);
                fsc[jj] = __expf(m[jj] - mn);
                m[jj] = mn;
            }
            float ls[4] = {0.f, 0.f, 0.f, 0.f};
            unsigned short pw[4][4];
            #pragma unroll
            for (int nf = 0; nf < 4; ++nf)
                #pragma unroll
                for (int jj = 0; jj < 4; ++jj) {
                    float p = __expf(sf[nf][jj] - m[jj]);
                    ls[jj] += p;
                    pw[nf][jj] = f2bf(p);
                }
            #pragma unroll
            for (int jj = 0; jj < 4; ++jj) {
                float s4 = ls[jj];
                s4 += __shfl_xor(s4, 1);
                s4 += __shfl_xor(s4, 2);
                s4 += __shfl_xor(s4, 4);
                s4 += __shfl_xor(s4, 8);
                lsum[jj] = lsum[jj] * fsc[jj] + s4;
            }
            #pragma unroll
            for (int nf = 0; nf < 4; ++nf)
                #pragma unroll
                for (int jj = 0; jj < 4; ++jj)
                    o[nf][jj] *= fsc[jj];

            // ---- write P tile (bf16, swizzled; rows wave-private, no barrier) ----
            #pragma unroll
            for (int nf = 0; nf < 4; ++nf)
                #pragma unroll
                for (int jj = 0; jj < 4; ++jj) {
                    int qq = w * 16 + (l >> 4) * 4 + jj;
                    int cb = 2 * (nf * 16 + lid);
                    *(unsigned short*)(Pt + qq * 128 + (cb ^ ((qq & 7) << 4))) = pw[nf][jj];
                }

            // ---- O += P V ----
            #pragma unroll
            for (int ks = 0; ks < 2; ++ks) {
                int cb = ks * 64 + hi;
                int qr = w * 16 + lid;
                bf16x8 pa = *(const bf16x8*)(Pt + qr * 128 + (cb ^ ((qr & 7) << 4)));
                #pragma unroll
                for (int nf = 0; nf < 4; ++nf) {
                    int dr = nf * 16 + lid;
                    bf16x8 vb = *(const bf16x8*)(Vt[cur] + dr * 128 + (cb ^ ((dr & 7) << 4)));
                    o[nf] = MFMA_B16(pa, vb, o[nf]);
                }
            }

            __syncthreads();   // drains staged loads; protects buffer reuse
        }

        // ---- epilogue: AO bf16 [b*S+s][h*64+d] ----
        float inv[4];
        #pragma unroll
        for (int jj = 0; jj < 4; ++jj) inv[jj] = 1.0f / lsum[jj];
        #pragma unroll
        for (int nf = 0; nf < 4; ++nf)
            #pragma unroll
            for (int jj = 0; jj < 4; ++jj) {
                int srow = q0 + w * 16 + (l >> 4) * 4 + jj;
                int col  = h * 64 + nf * 16 + lid;
                AOb[((size_t)b * SEQ + srow) * DM + col] = f2bf(o[nf][jj] * inv[jj]);
            }
    }
}

// ---------------- launch ----------------
extern "C" void kernel_launch(void* const* d_in, const int* in_sizes, int n_in,
                              void* d_out, int out_size, void* d_ws, size_t ws_size,
                              hipStream_t stream)
{
    const float* x   = (const float*)d_in[0];
    const int*   pos = (const int*)  d_in[1];
    const float* Wq  = (const float*)d_in[2];
    const float* Wk  = (const float*)d_in[3];
    const float* Wv  = (const float*)d_in[4];
    const float* Wo  = (const float*)d_in[5];
    float* out = (float*)d_out;

    const size_t M1 = 1u << 20;                 // 1M elements
    unsigned short* ws  = (unsigned short*)d_ws;
    unsigned short* Xb    = ws;                 // 4M
    unsigned short* Wqkvb = ws + 4 * M1;        // 3M (Wq|Wk|Wv rows)
    unsigned short* Wob   = ws + 7 * M1;        // 1M
    unsigned short* Qbf   = ws + 8 * M1;        // 4M  [bh][s][64]
    unsigned short* Kbf   = ws + 12 * M1;       // 4M  [bh][s][64]
    unsigned short* VTb   = ws + 16 * M1;       // 4M  [bh][64][s]
    unsigned short* AOb   = ws + 20 * M1;       // 4M  [b*s][1024]
    // total 48 MB

    // fp32 -> bf16 (single launch: x + Wq + Wk + Wv + Wo)
    convert_all<<<8192, 256, 0, stream>>>(x, Wq, Wk, Wv, Wo, Xb, Wqkvb, Wob);

    // QKV projection (epilogue scatters Q,K row-major; V transposed)
    gemm_mfma<0><<<dim3(24, 32), 256, 0, stream>>>(Xb, Wqkvb, Qbf, Kbf, VTb, nullptr);

    // RoPE in place on bf16 Q/K
    rope_bf16<<<8192, 256, 0, stream>>>(Qbf, Kbf, pos);

    // flash attention (balanced q-tile pairs)
    flash_mfma<<<dim3(SEQ / 128, BATCH * NH), 256, 0, stream>>>(Qbf, Kbf, VTb, AOb);

    // output projection
    gemm_mfma<1><<<dim3(8, 32), 256, 0, stream>>>(AOb, Wob, nullptr, nullptr, nullptr, out);
}

// Round 9
// 142.263 us; speedup vs baseline: 40.6304x; 1.1101x over previous
//
#include <hip/hip_runtime.h>
#include <math.h>

#define SEQ   2048
#define BATCH 2
#define NH    16
#define DKD   64
#define DM    1024
#define MTOT  (BATCH*SEQ)   // 4096

typedef short bf16x8 __attribute__((ext_vector_type(8)));      // 8 bf16 (4 VGPR)
typedef float f32x4  __attribute__((ext_vector_type(4)));      // MFMA C/D
typedef unsigned short u16x4 __attribute__((ext_vector_type(4)));

#define MFMA_B16(a,b,c) __builtin_amdgcn_mfma_f32_16x16x32_bf16((a),(b),(c),0,0,0)

__device__ __forceinline__ unsigned short f2bf(float f) {
    union { float f; unsigned int u; } v; v.f = f;
    unsigned int r = v.u + 0x7FFFu + ((v.u >> 16) & 1u);   // RNE
    return (unsigned short)(r >> 16);
}
__device__ __forceinline__ float bf2f(unsigned short h) {
    union { unsigned int u; float f; } v; v.u = ((unsigned int)h) << 16;
    return v.f;
}
__device__ __forceinline__ void gload16(const void* g, void* l) {
    __builtin_amdgcn_global_load_lds(
        (const __attribute__((address_space(1))) unsigned int*)g,
        (__attribute__((address_space(3))) unsigned int*)l, 16, 0, 0);
}

// ---------------- fp32 -> bf16: x + Wq + Wk + Wv + Wo in ONE launch ----------------
__global__ __launch_bounds__(256)
void convert_all(const float* __restrict__ x,  const float* __restrict__ Wq,
                 const float* __restrict__ Wk, const float* __restrict__ Wv,
                 const float* __restrict__ Wo,
                 unsigned short* __restrict__ Xb, unsigned short* __restrict__ Wqkvb,
                 unsigned short* __restrict__ Wob)
{
    int i = blockIdx.x * 256 + threadIdx.x;          // 0 .. 2M-1
    const float* src;
    unsigned short* dst;
    size_t off;
    if (i < (1 << 20)) {
        src = x; dst = Xb; off = (size_t)i;
    } else {
        int j = i - (1 << 20);
        int wsel = j >> 18;                          // 0..3
        off = (size_t)(j & ((1 << 18) - 1));
        src = (wsel == 0) ? Wq : (wsel == 1) ? Wk : (wsel == 2) ? Wv : Wo;
        dst = (wsel < 3) ? Wqkvb + (size_t)wsel * (1u << 20) : Wob;
    }
    float4 v = ((const float4*)src)[off];
    u16x4 o = { f2bf(v.x), f2bf(v.y), f2bf(v.z), f2bf(v.w) };
    *(u16x4*)&dst[off * 4] = o;
}

// ---------------- RoPE in place on bf16 Q/K  [bh][s][64] ----------------
__global__ __launch_bounds__(256)
void rope_bf16(unsigned short* __restrict__ Qb, unsigned short* __restrict__ Kb,
               const int* __restrict__ pos)
{
    int g = blockIdx.x * 256 + threadIdx.x;      // 2M ushort4-groups (Q then K)
    int tsel = g >> 20;
    int i = g & ((1 << 20) - 1);
    unsigned short* base = tsel ? Kb : Qb;
    int d4 = i & 15;
    int s  = (i >> 4) & (SEQ - 1);
    float P = (float)pos[s];
    const float NEG_L2 = -0.41524101186092103f;  // -log2(10000)/32
    int p0 = d4 * 2, p1 = p0 + 1;
    float a0 = P * exp2f((float)p0 * NEG_L2);
    float a1 = P * exp2f((float)p1 * NEG_L2);
    float s0, c0, s1, c1;
    sincosf(a0, &s0, &c0);
    sincosf(a1, &s1, &c1);

    u16x4 v = *(u16x4*)&base[(size_t)i * 4];
    float x0 = bf2f(v[0]), x1 = bf2f(v[1]), x2 = bf2f(v[2]), x3 = bf2f(v[3]);
    u16x4 o = { f2bf(x0 * c0 - x1 * s0), f2bf(x0 * s0 + x1 * c0),
                f2bf(x2 * c1 - x3 * s1), f2bf(x2 * s1 + x3 * c1) };
    *(u16x4*)&base[(size_t)i * 4] = o;
}

// ---------------- MFMA GEMM (unchanged from R8) ----------------
template<int MODE>
__global__ __launch_bounds__(256)
void gemm_mfma(const unsigned short* __restrict__ A, const unsigned short* __restrict__ B,
               unsigned short* __restrict__ Qb, unsigned short* __restrict__ Kb,
               unsigned short* __restrict__ VTb, float* __restrict__ Cf)
{
    const int t = threadIdx.x;
    const int w = t >> 6, l = t & 63, lid = l & 15, hi = (l >> 4) * 16;
    const int wm = w >> 1, wn = w & 1;
    const int m0 = blockIdx.y * 128, n0 = blockIdx.x * 128;

    __shared__ __align__(16) char At[2][8192];
    __shared__ __align__(16) char Bt[2][8192];

    f32x4 acc[4][4];
    const f32x4 z4 = {0.f, 0.f, 0.f, 0.f};
    #pragma unroll
    for (int i = 0; i < 4; ++i)
        #pragma unroll
        for (int j = 0; j < 4; ++j) acc[i][j] = z4;

    const char* Ab = (const char*)A;
    const char* Bb = (const char*)B;

    auto stage = [&](int buf, int kt) {
        const int kbyte = kt * 64;
        #pragma unroll
        for (int i = 0; i < 2; ++i) {
            int o   = i * 4096 + t * 16;
            int row = o >> 6, cb = o & 63;
            char* lbase_a = At[buf] + i * 4096 + (t >> 6) * 1024;
            char* lbase_b = Bt[buf] + i * 4096 + (t >> 6) * 1024;
            gload16(Ab + (size_t)(m0 + row) * 2048 + kbyte + cb, lbase_a);
            gload16(Bb + (size_t)(n0 + row) * 2048 + kbyte + cb, lbase_b);
        }
    };

    stage(0, 0);
    __syncthreads();

    const int NKT = DM / 32;
    for (int kt = 0; kt < NKT; ++kt) {
        const int cur = kt & 1;
        if (kt + 1 < NKT) stage(cur ^ 1, kt + 1);

        bf16x8 af[4], bfr[4];
        #pragma unroll
        for (int mf = 0; mf < 4; ++mf)
            af[mf] = *(const bf16x8*)(At[cur] + (wm * 64 + mf * 16 + lid) * 64 + hi);
        #pragma unroll
        for (int nf = 0; nf < 4; ++nf)
            bfr[nf] = *(const bf16x8*)(Bt[cur] + (wn * 64 + nf * 16 + lid) * 64 + hi);
        __builtin_amdgcn_s_setprio(1);
        #pragma unroll
        for (int mf = 0; mf < 4; ++mf)
            #pragma unroll
            for (int nf = 0; nf < 4; ++nf)
                acc[mf][nf] = MFMA_B16(af[mf], bfr[nf], acc[mf][nf]);
        __builtin_amdgcn_s_setprio(0);

        __syncthreads();
    }

    if (MODE == 1) {
        #pragma unroll
        for (int mf = 0; mf < 4; ++mf)
            #pragma unroll
            for (int nf = 0; nf < 4; ++nf) {
                int ncol = n0 + wn * 64 + nf * 16 + lid;
                #pragma unroll
                for (int jj = 0; jj < 4; ++jj) {
                    int mrow = m0 + wm * 64 + mf * 16 + (l >> 4) * 4 + jj;
                    Cf[(size_t)mrow * DM + ncol] = acc[mf][nf][jj];
                }
            }
    } else {
        const int z = n0 >> 10;                  // 0:Q 1:K 2:V
        const int nbase = n0 & 1023;
        #pragma unroll
        for (int mf = 0; mf < 4; ++mf)
            #pragma unroll
            for (int nf = 0; nf < 4; ++nf) {
                int ncol = nbase + wn * 64 + nf * 16 + lid;
                int h = ncol >> 6, d = ncol & 63;
                int mbase = m0 + wm * 64 + mf * 16 + (l >> 4) * 4;
                int b = mbase >> 11, s0v = mbase & 2047;
                if (z == 2) {
                    u16x4 pk = { f2bf(acc[mf][nf][0]), f2bf(acc[mf][nf][1]),
                                 f2bf(acc[mf][nf][2]), f2bf(acc[mf][nf][3]) };
                    *(u16x4*)&VTb[((size_t)(b * NH + h) * DKD + d) * SEQ + s0v] = pk;
                } else {
                    unsigned short* dst = (z == 0) ? Qb : Kb;
                    #pragma unroll
                    for (int jj = 0; jj < 4; ++jj)
                        dst[((size_t)(b * NH + h) * SEQ + (s0v + jj)) * DKD + d] =
                            f2bf(acc[mf][nf][jj]);
                }
            }
    }
}

// ---------------- MFMA flash attention, swapped-QK^T lane-local softmax ----------------
// grid (16, 32); block bx processes q-tiles (31-bx) then (bx): 33 tile-iters/block.
// S computed as mfma(K,Q) -> lane holds S[key][q=lane&15]: row softmax is in-lane
// (15 fmax + 2 shfl), P-write is 4x ds_write_b64 via v_cvt_pk_bf16_f32.
__global__ __launch_bounds__(256)
void flash_mfma(const unsigned short* __restrict__ Qb, const unsigned short* __restrict__ Kb,
                const unsigned short* __restrict__ VTb, unsigned short* __restrict__ AOb)
{
    const int bh = blockIdx.y;
    const int b = bh >> 4, h = bh & 15;
    const int t = threadIdx.x, w = t >> 6, l = t & 63, lid = l & 15, hi = (l >> 4) * 16;
    const int h4 = l >> 4;

    __shared__ __align__(16) char Kt[2][8192];
    __shared__ __align__(16) char Vt[2][8192];
    __shared__ __align__(16) char Pt[8192];

    const char* Kbh = (const char*)(Kb  + (size_t)bh * SEQ * DKD);
    const char* Vbh = (const char*)(VTb + (size_t)bh * SEQ * DKD);
    const char* Qbh = (const char*)(Qb  + (size_t)bh * SEQ * DKD);

    const f32x4 z4 = {0.f, 0.f, 0.f, 0.f};
    const int qrow = w * 16 + lid;
    const float CLOG = 0.18033688011112042f;     // log2(e)/8

    #pragma unroll 1
    for (int phase = 0; phase < 2; ++phase) {
        const int qb = phase ? (int)blockIdx.x : (31 - (int)blockIdx.x);  // heavy first
        const int q0 = qb * 64;

        bf16x8 qf[2];
        qf[0] = *(const bf16x8*)(Qbh + (size_t)(q0 + qrow) * 128 + 0  + hi);
        qf[1] = *(const bf16x8*)(Qbh + (size_t)(q0 + qrow) * 128 + 64 + hi);

        f32x4 o[4];
        #pragma unroll
        for (int nf = 0; nf < 4; ++nf) o[nf] = z4;
        float m0 = -1e30f;      // running max (raw score domain) for q = w*16+lid
        float lsum0 = 0.f;      // running denom for q = w*16+lid

        auto stage = [&](int buf, int kt) {
            const int k0 = kt * 64;
            #pragma unroll
            for (int i = 0; i < 2; ++i) {
                int o_   = i * 4096 + t * 16;
                int row  = o_ >> 7, cl = o_ & 127;
                int sw   = (row & 7) << 4;
                char* lK = Kt[buf] + i * 4096 + (t >> 6) * 1024;
                char* lV = Vt[buf] + i * 4096 + (t >> 6) * 1024;
                gload16(Kbh + (size_t)(k0 + row) * 128 + (cl ^ sw), lK);
                gload16(Vbh + (size_t)row * (SEQ * 2) + k0 * 2 + (cl ^ sw), lV);
            }
        };

        const int nt = qb + 1;
        stage(0, 0);
        __syncthreads();

        for (int kt = 0; kt < nt; ++kt) {
            const int cur = kt & 1;
            if (kt + 1 < nt) stage(cur ^ 1, kt + 1);

            // ---- S^T = K Q^T : lane holds S[key=nf*16+4*h4+jj][q=w*16+lid] ----
            f32x4 sf[4];
            #pragma unroll
            for (int nf = 0; nf < 4; ++nf) {
                f32x4 a = z4;
                #pragma unroll
                for (int ks = 0; ks < 2; ++ks) {
                    int r  = nf * 16 + lid;
                    int cb = ks * 64 + hi;
                    bf16x8 kfr = *(const bf16x8*)(Kt[cur] + r * 128 + (cb ^ ((r & 7) << 4)));
                    __builtin_amdgcn_s_setprio(1);
                    a = MFMA_B16(kfr, qf[ks], a);          // swapped operands
                    __builtin_amdgcn_s_setprio(0);
                }
                sf[nf] = a;
            }

            // ---- causal mask on the diagonal tile (raw domain) ----
            if (kt == qb) {
                const int qloc = w * 16 + lid;
                #pragma unroll
                for (int nf = 0; nf < 4; ++nf) {
                    #pragma unroll
                    for (int jj = 0; jj < 4; ++jj) {
                        int keyloc = nf * 16 + h4 * 4 + jj;
                        if (keyloc > qloc) sf[nf][jj] = -1e30f;
                    }
                }
            }

            // ---- online softmax: row is lane-local over 16 regs + 2 shuffles ----
            float tm = -1e30f;
            #pragma unroll
            for (int nf = 0; nf < 4; ++nf) {
                float a0 = fmaxf(sf[nf][0], sf[nf][1]);
                float a1 = fmaxf(sf[nf][2], sf[nf][3]);
                tm = fmaxf(tm, fmaxf(a0, a1));
            }
            tm = fmaxf(tm, __shfl_xor(tm, 16));
            tm = fmaxf(tm, __shfl_xor(tm, 32));

            bool noresc = __all(tm <= m0 + 32.0f);         // defer-max (raw THR=32)
            float fsc = 1.0f;
            if (!noresc) {
                float mn = fmaxf(m0, tm);
                fsc = exp2f((m0 - mn) * CLOG);
                m0 = mn;
            }
            float nmc = -m0 * CLOG;

            float s4 = 0.f;
            uint2 pk[4];
            #pragma unroll
            for (int nf = 0; nf < 4; ++nf) {
                float p0 = exp2f(fmaf(sf[nf][0], CLOG, nmc));
                float p1 = exp2f(fmaf(sf[nf][1], CLOG, nmc));
                float p2 = exp2f(fmaf(sf[nf][2], CLOG, nmc));
                float p3 = exp2f(fmaf(sf[nf][3], CLOG, nmc));
                s4 += (p0 + p1) + (p2 + p3);
                unsigned plo, phi;
                asm("v_cvt_pk_bf16_f32 %0, %1, %2" : "=v"(plo) : "v"(p0), "v"(p1));
                asm("v_cvt_pk_bf16_f32 %0, %1, %2" : "=v"(phi) : "v"(p2), "v"(p3));
                pk[nf].x = plo; pk[nf].y = phi;
            }
            s4 += __shfl_xor(s4, 16);
            s4 += __shfl_xor(s4, 32);
            lsum0 = lsum0 * fsc + s4;

            if (!noresc) {
                float fr[4];
                #pragma unroll
                for (int jj = 0; jj < 4; ++jj) fr[jj] = __shfl(fsc, h4 * 4 + jj);
                #pragma unroll
                for (int nf = 0; nf < 4; ++nf)
                    #pragma unroll
                    for (int jj = 0; jj < 4; ++jj) o[nf][jj] *= fr[jj];
            }

            // ---- write P row-chunk: 4 consecutive keys per lane, b64 stores ----
            {
                const int rowq = w * 16 + lid;
                const int swz  = (lid & 7) << 4;
                char* base = Pt + rowq * 128;
                #pragma unroll
                for (int nf = 0; nf < 4; ++nf)
                    *(uint2*)(base + ((nf * 32 + 8 * h4) ^ swz)) = pk[nf];
            }

            // ---- O += P V (unchanged: pa reads P[q][k] contiguous) ----
            #pragma unroll
            for (int ks = 0; ks < 2; ++ks) {
                int cb = ks * 64 + hi;
                int qr = w * 16 + lid;
                bf16x8 pa = *(const bf16x8*)(Pt + qr * 128 + (cb ^ ((qr & 7) << 4)));
                __builtin_amdgcn_s_setprio(1);
                #pragma unroll
                for (int nf = 0; nf < 4; ++nf) {
                    int dr = nf * 16 + lid;
                    bf16x8 vb = *(const bf16x8*)(Vt[cur] + dr * 128 + (cb ^ ((dr & 7) << 4)));
                    o[nf] = MFMA_B16(pa, vb, o[nf]);
                }
                __builtin_amdgcn_s_setprio(0);
            }

            __syncthreads();   // drains staged loads; protects buffer reuse
        }

        // ---- epilogue: AO bf16 [b*S+s][h*64+d]; lsum fetched per o-row ----
        float inv[4];
        #pragma unroll
        for (int jj = 0; jj < 4; ++jj) inv[jj] = 1.0f / __shfl(lsum0, h4 * 4 + jj);
        #pragma unroll
        for (int nf = 0; nf < 4; ++nf)
            #pragma unroll
            for (int jj = 0; jj < 4; ++jj) {
                int srow = q0 + w * 16 + h4 * 4 + jj;
                int col  = h * 64 + nf * 16 + lid;
                AOb[((size_t)b * SEQ + srow) * DM + col] = f2bf(o[nf][jj] * inv[jj]);
            }
    }
}

// ---------------- launch ----------------
extern "C" void kernel_launch(void* const* d_in, const int* in_sizes, int n_in,
                              void* d_out, int out_size, void* d_ws, size_t ws_size,
                              hipStream_t stream)
{
    const float* x   = (const float*)d_in[0];
    const int*   pos = (const int*)  d_in[1];
    const float* Wq  = (const float*)d_in[2];
    const float* Wk  = (const float*)d_in[3];
    const float* Wv  = (const float*)d_in[4];
    const float* Wo  = (const float*)d_in[5];
    float* out = (float*)d_out;

    const size_t M1 = 1u << 20;                 // 1M elements
    unsigned short* ws  = (unsigned short*)d_ws;
    unsigned short* Xb    = ws;                 // 4M
    unsigned short* Wqkvb = ws + 4 * M1;        // 3M (Wq|Wk|Wv rows)
    unsigned short* Wob   = ws + 7 * M1;        // 1M
    unsigned short* Qbf   = ws + 8 * M1;        // 4M  [bh][s][64]
    unsigned short* Kbf   = ws + 12 * M1;       // 4M  [bh][s][64]
    unsigned short* VTb   = ws + 16 * M1;       // 4M  [bh][64][s]
    unsigned short* AOb   = ws + 20 * M1;       // 4M  [b*s][1024]

    convert_all<<<8192, 256, 0, stream>>>(x, Wq, Wk, Wv, Wo, Xb, Wqkvb, Wob);

    gemm_mfma<0><<<dim3(24, 32), 256, 0, stream>>>(Xb, Wqkvb, Qbf, Kbf, VTb, nullptr);

    rope_bf16<<<8192, 256, 0, stream>>>(Qbf, Kbf, pos);

    flash_mfma<<<dim3(SEQ / 128, BATCH * NH), 256, 0, stream>>>(Qbf, Kbf, VTb, AOb);

    gemm_mfma<1><<<dim3(8, 32), 256, 0, stream>>>(AOb, Wob, nullptr, nullptr, nullptr, out);
}